// Round 14
// baseline (189.701 us; speedup 1.0000x reference)
//
#include <hip/hip_runtime.h>
#include <hip/hip_bf16.h>
#include <stdint.h>

// CrossAttention: out = softmax((x@Wq)(ctx@Wk)^T * scale) @ (ctx@Wv) @ Wo + bo
// B=16, NQ=4096, NK=77, QD=512, CD=768, H=8, DH=64, INNER=512
//
// Round 14: single isolated fix vs round 13 — Vt/Vtg stride 96 -> 104.
// Stride 96 (192 B) rows map to bank 16r mod 32: every even row of a 16-row
// MFMA fragment read hits the SAME bank = 8-way conflict on the 12 PV
// ds_read_b128/wave/iter (matches the measured 11.9M conflict cycles).
// Stride 104 (208 B -> 20r mod 32) is 2-way = free (proven in attn3 r10-12).
// LDS phase-2 map: Qh 36864 | Kl 23040 | Vt 26624 | Pw 40960 = 127488 B.

typedef __attribute__((ext_vector_type(8))) short bf16x8;
typedef __attribute__((ext_vector_type(4))) float f32x4;
typedef __attribute__((ext_vector_type(4))) short short4v;
typedef __attribute__((ext_vector_type(4))) float float4v;
typedef __attribute__((ext_vector_type(2))) unsigned uint2v;
typedef __attribute__((ext_vector_type(4))) unsigned uint4v;

#define DEVINL __device__ __forceinline__

DEVINL short f2bf(float f) {
  unsigned u = __builtin_bit_cast(unsigned, f);
  unsigned r = (u + 0x7FFFu + ((u >> 16) & 1u)) >> 16;  // RNE
  return (short)(unsigned short)r;
}

// packed f32x2 -> bf16x2 (RTNE), single VALU op
DEVINL unsigned pkbf(float lo, float hi) {
  unsigned r;
  asm("v_cvt_pk_bf16_f32 %0, %1, %2" : "=v"(r) : "v"(lo), "v"(hi));
  return r;
}

#define GLDS16(gp, sp)                                                \
  __builtin_amdgcn_global_load_lds(                                   \
      (const __attribute__((address_space(1))) void*)(gp),            \
      (__attribute__((address_space(3))) void*)(sp), 16, 0, 0)

// ---------------- batched prep: 4x weight transpose + Vtg zero-fill --------
// grid (8, 12, 5). z=0..3: W[K][512] f32 -> Wt[512][K] bf16 (kt guard).
// z=4: zero-fill Vtg (106496 float4 granules, grid-stride).
__global__ __launch_bounds__(256) void prep_all(
    const float* __restrict__ Wq, const float* __restrict__ Wk,
    const float* __restrict__ Wv, const float* __restrict__ Wo,
    short* __restrict__ wqt, short* __restrict__ wkt,
    short* __restrict__ wvt, short* __restrict__ wot,
    float4v* __restrict__ vfill) {
  const int z = blockIdx.z;
  if (z == 4) {
    for (int i = (blockIdx.y * 8 + blockIdx.x) * 256 + threadIdx.x;
         i < 106496; i += 24576)
      vfill[i] = float4v{0.f, 0.f, 0.f, 0.f};
    return;
  }
  const float* W;
  short* Wt;
  int K;
  switch (z) {
    case 0: W = Wq; Wt = wqt; K = 512; break;
    case 1: W = Wk; Wt = wkt; K = 768; break;
    case 2: W = Wv; Wt = wvt; K = 768; break;
    default: W = Wo; Wt = wot; K = 512; break;
  }
  const int kt = blockIdx.y * 64;
  if (kt >= K) return;
  const int nt = blockIdx.x * 64;

  __shared__ short Tl[64][65];
#pragma unroll
  for (int i = 0; i < 16; ++i) {
    int idx = threadIdx.x + i * 256;
    int r = idx >> 6, c = idx & 63;
    Tl[c][r] = f2bf(W[(size_t)(kt + r) * 512 + nt + c]);
  }
  __syncthreads();
#pragma unroll
  for (int i = 0; i < 16; ++i) {
    int idx = threadIdx.x + i * 256;
    int r = idx >> 6, c = idx & 63;
    Wt[(size_t)(nt + r) * K + kt + c] = Tl[r][c];
  }
}

// ---------------- K+V projections in one dispatch ---------------------------
// grid (4, 39, 2). z=0: Kb[M][512] bf16 = ctx @ wkt^T.
// z=1: V scatter -> Vtg[((b*8+h)*64+d)*104 + key] (pads pre-zeroed).
__global__ __launch_bounds__(256) void kvproj(const float* __restrict__ A,
                                              const short* __restrict__ wkt,
                                              const short* __restrict__ wvt,
                                              short* __restrict__ Kb,
                                              short* __restrict__ Vtg) {
  __shared__ short Al[32][40];
  __shared__ short Bl[128][40];

  const int TRANS = blockIdx.z;
  const short* Bt = TRANS ? wvt : wkt;

  const int tid = threadIdx.x;
  const int lane = tid & 63, wid = tid >> 6;
  const int wm = wid >> 1, wn = wid & 1;
  const int quad = lane >> 4, l16 = lane & 15;
  const int m0 = blockIdx.y * 32, n0 = blockIdx.x * 128;
  const int M = 1232, K = 768;

  f32x4 acc[4] = {};

  for (int k0 = 0; k0 < K; k0 += 32) {
    for (int idx = tid; idx < 32 * 8; idx += 256) {
      int row = idx >> 3, kq = idx & 7;
      float4v v = {};
      if (m0 + row < M)
        v = *(const float4v*)(A + (size_t)(m0 + row) * K + k0 + kq * 4);
      short4v s = {f2bf(v[0]), f2bf(v[1]), f2bf(v[2]), f2bf(v[3])};
      *(short4v*)&Al[row][kq * 4] = s;
    }
    for (int idx = tid; idx < 512; idx += 256) {
      int row = idx >> 2, kq = idx & 3;
      *(bf16x8*)&Bl[row][kq * 8] =
          *(const bf16x8*)(Bt + (size_t)(n0 + row) * K + k0 + kq * 8);
    }
    __syncthreads();

    bf16x8 a = *(bf16x8*)&Al[wm * 16 + l16][quad * 8];
#pragma unroll
    for (int n = 0; n < 4; ++n) {
      bf16x8 b = *(bf16x8*)&Bl[wn * 64 + n * 16 + l16][quad * 8];
      acc[n] = __builtin_amdgcn_mfma_f32_16x16x32_bf16(a, b, acc[n], 0, 0, 0);
    }
    __syncthreads();
  }

#pragma unroll
  for (int n = 0; n < 4; ++n) {
    const int col = n0 + wn * 64 + n * 16 + l16;
    const int rowb = m0 + wm * 16 + quad * 4;
#pragma unroll
    for (int r = 0; r < 4; ++r) {
      const int rr = rowb + r;
      if (rr < M) {
        if (!TRANS) {
          Kb[(size_t)rr * 512 + col] = f2bf(acc[n][r]);
        } else {
          const int bb = rr / 77, key = rr - bb * 77;
          Vtg[(size_t)((bb * 8 + (col >> 6)) * 64 + (col & 63)) * 104 + key] =
              f2bf(acc[n][r]);
        }
      }
    }
  }
}

// ---------------- fused Q-proj + attention ---------------------------------
// 1024 thr (16 waves). Phase 1: BK=32, 16 steps, LDS double-buffer
// (xb[2][128][40], wsW[2][512][40]), reg-staged, prefetch after barrier,
// ONE __syncthreads per step. Phase 2: 4 iters x 2 heads; Vt stride 104.
__global__ __launch_bounds__(1024, 4) void qattn(const float* __restrict__ x,
                                                 const short* __restrict__ wqt,
                                                 const short* __restrict__ Kb,
                                                 const short* __restrict__ Vtg,
                                                 short* __restrict__ AOb) {
  __shared__ __align__(16) char smem[127488];
  short* xb  = (short*)smem;               // ph1: [2][128][40] bf16, 20480 B
  short* wsW = (short*)(smem + 20480);     // ph1: [2][512][40] bf16, 81920 B
  short* Qh  = (short*)smem;               // ph2: [2][128][72], 36864 B
  short* Kl  = (short*)(smem + 36864);     // ph2: [2][80][72], 23040 B
  short* Vt  = (short*)(smem + 59904);     // ph2: [2][64][104], 26624 B
  short* Pw  = (short*)(smem + 86528);     // ph2: [16][16][80], 40960 B

  const int tid = threadIdx.x;
  const int lane = tid & 63, w = tid >> 6;
  const int wm = w >> 3, wn = w & 7;
  const int quad = lane >> 4, l16 = lane & 15;
  const int m0 = blockIdx.x * 128;
  const int b = m0 >> 12;

  f32x4 acc[4][4] = {};

  // ============ phase 1: Q projection, BK=32 pipelined (16 steps) ==========
  const int xrow = tid >> 3, xcol = (tid & 7) * 4;
  const int wr0 = tid >> 2, wc0 = (tid & 3) * 8;
  const int wr1 = (tid + 1024) >> 2, wc1 = wc0;

  const float* xg = x + (size_t)(m0 + xrow) * 512 + xcol;
  const short* wg0 = wqt + (size_t)wr0 * 512 + wc0;
  const short* wg1 = wqt + (size_t)wr1 * 512 + wc1;

  float4v px;
  bf16x8 pw0, pw1;
  px = *(const float4v*)(xg);
  pw0 = *(const bf16x8*)(wg0);
  pw1 = *(const bf16x8*)(wg1);

  for (int t = 0; t < 16; ++t) {
    short* xbuf = xb + (t & 1) * 5120;
    short* wbuf = wsW + (t & 1) * 20480;

    *(uint2v*)&xbuf[xrow * 40 + xcol] =
        uint2v{pkbf(px[0], px[1]), pkbf(px[2], px[3])};
    *(bf16x8*)&wbuf[wr0 * 40 + wc0] = pw0;
    *(bf16x8*)&wbuf[wr1 * 40 + wc1] = pw1;

    __syncthreads();

    if (t < 15) {
      const int k1 = (t + 1) * 32;
      px = *(const float4v*)(xg + k1);
      pw0 = *(const bf16x8*)(wg0 + k1);
      pw1 = *(const bf16x8*)(wg1 + k1);
    }

    bf16x8 af[4], bfr[4];
#pragma unroll
    for (int m = 0; m < 4; ++m)
      af[m] = *(bf16x8*)&xbuf[(wm * 64 + m * 16 + l16) * 40 + quad * 8];
#pragma unroll
    for (int n = 0; n < 4; ++n)
      bfr[n] = *(bf16x8*)&wbuf[(wn * 64 + n * 16 + l16) * 40 + quad * 8];
#pragma unroll
    for (int m = 0; m < 4; ++m)
#pragma unroll
      for (int n = 0; n < 4; ++n)
        acc[m][n] = __builtin_amdgcn_mfma_f32_16x16x32_bf16(af[m], bfr[n],
                                                            acc[m][n], 0, 0, 0);
  }
  __syncthreads();

  // ================= phase 2: 4 iters x 2 heads =================
#pragma unroll
  for (int it = 0; it < 4; ++it) {
    if (it) __syncthreads();

    if ((wn >> 1) == it) {
      const int slot = wn & 1;
#pragma unroll
      for (int m = 0; m < 4; ++m)
#pragma unroll
        for (int n = 0; n < 4; ++n)
#pragma unroll
          for (int r = 0; r < 4; ++r)
            Qh[slot * 9216 + (wm * 64 + m * 16 + quad * 4 + r) * 72 +
               n * 16 + l16] = f2bf(acc[m][n][r]);
    }
    for (int idx = tid; idx < 1232; idx += 1024) {
      const int sk = idx >= 616;
      const int e = idx - sk * 616;
      const int r = e >> 3, cc = (e & 7) * 8;
      *(bf16x8*)&Kl[sk * 5760 + r * 72 + cc] =
          *(const bf16x8*)(Kb + ((size_t)b * 77 + r) * 512 +
                           (it * 2 + sk) * 64 + cc);
    }
    // V^T stage x2 heads, linear GLDS: 13 chunks of 1 KB per head
    for (int cid = w; cid < 26; cid += 16) {
      const int sv = cid >= 13;
      const int c13 = cid - sv * 13;
      GLDS16(Vtg + (size_t)(b * 8 + it * 2 + sv) * 6656 + c13 * 512 + lane * 8,
             Vt + sv * 6656 + c13 * 512);
    }
    __syncthreads();

    bf16x8 qfr[2];
#pragma unroll
    for (int ks = 0; ks < 2; ++ks)
      qfr[ks] = *(bf16x8*)&Qh[wm * 9216 + (wn * 16 + l16) * 72 +
                              ks * 32 + quad * 8];

    f32x4 c[5] = {};
#pragma unroll
    for (int f = 0; f < 5; ++f)
#pragma unroll
      for (int ks = 0; ks < 2; ++ks) {
        bf16x8 a = *(bf16x8*)&Kl[wm * 5760 + (f * 16 + l16) * 72 +
                                 ks * 32 + quad * 8];
        c[f] = __builtin_amdgcn_mfma_f32_16x16x32_bf16(a, qfr[ks], c[f], 0, 0, 0);
      }

    float mx = -1e30f;
#pragma unroll
    for (int f = 0; f < 5; ++f)
#pragma unroll
      for (int r = 0; r < 4; ++r) {
        const int key = f * 16 + quad * 4 + r;
        float v = c[f][r] * 0.125f;
        v = (key < 77) ? v : -1e30f;
        c[f][r] = v;
        mx = fmaxf(mx, v);
      }
    mx = fmaxf(mx, __shfl_xor(mx, 16));
    mx = fmaxf(mx, __shfl_xor(mx, 32));

    short* pbase = Pw + (w * 16 + l16) * 80;
    float sum = 0.f;
#pragma unroll
    for (int f = 0; f < 5; ++f) {
      float e0 = __expf(c[f][0] - mx), e1 = __expf(c[f][1] - mx);
      float e2 = __expf(c[f][2] - mx), e3 = __expf(c[f][3] - mx);
      sum += (e0 + e1) + (e2 + e3);
      uint2v sv2 = {pkbf(e0, e1), pkbf(e2, e3)};
      *(uint2v*)(pbase + f * 16 + quad * 4) = sv2;
    }
    sum += __shfl_xor(sum, 16);
    sum += __shfl_xor(sum, 32);
    const float inv = 1.0f / sum;

    bf16x8 pb0 = *(bf16x8*)(pbase + quad * 8);
    bf16x8 pb1 = *(bf16x8*)(pbase + 32 + quad * 8);
    bf16x8 pb2 = bf16x8{0, 0, 0, 0, 0, 0, 0, 0};
    if (quad < 2) pb2 = *(bf16x8*)(pbase + 64 + quad * 8);

    f32x4 o[4] = {};
#pragma unroll
    for (int mt = 0; mt < 4; ++mt) {
      const short* vrow = &Vt[wm * 6656 + (mt * 16 + l16) * 104];
      o[mt] = __builtin_amdgcn_mfma_f32_16x16x32_bf16(
          *(bf16x8*)(vrow + quad * 8), pb0, o[mt], 0, 0, 0);
      o[mt] = __builtin_amdgcn_mfma_f32_16x16x32_bf16(
          *(bf16x8*)(vrow + 32 + quad * 8), pb1, o[mt], 0, 0, 0);
      o[mt] = __builtin_amdgcn_mfma_f32_16x16x32_bf16(
          *(bf16x8*)(vrow + 64 + quad * 8), pb2, o[mt], 0, 0, 0);
    }

    short* op = AOb + ((size_t)m0 + wn * 16 + l16) * 512 + (it * 2 + wm) * 64;
#pragma unroll
    for (int mt = 0; mt < 4; ++mt) {
      uint2v sv2 = {pkbf(o[mt][0] * inv, o[mt][1] * inv),
                    pkbf(o[mt][2] * inv, o[mt][3] * inv)};
      *(uint2v*)(op + mt * 16 + quad * 4) = sv2;
    }
  }
}

// ---------------- O-proj: 2-phase dbuf GEMM, bf16 A/B ----------------------
__global__ __launch_bounds__(256) void gemm2(const short* __restrict__ A,
                                             const short* __restrict__ Bt,
                                             float* __restrict__ C,
                                             const float* __restrict__ bias) {
  __shared__ short As[2][128 * 64];
  __shared__ short Bs[2][128 * 64];

  const int tid = threadIdx.x;
  const int lane = tid & 63, w = tid >> 6;
  const int wm = w >> 1, wn = w & 1;
  const int quad = lane >> 4, l16 = lane & 15;

  const int cpx = gridDim.x >> 3;
  const int swz = (blockIdx.x & 7) * cpx + (blockIdx.x >> 3);
  const int m0 = (swz >> 2) * 128, n0 = (swz & 3) * 128;

  const int lr = lane >> 3, lc = (lane & 7) * 8;

  f32x4 acc[4][4] = {};

#pragma unroll
  for (int p = 0; p < 4; ++p) {
    const int rowb = w * 32 + p * 8;
    GLDS16(A + (size_t)(m0 + rowb + lr) * 512 + lc, &As[0][rowb * 64]);
    GLDS16(Bt + (size_t)(n0 + rowb + lr) * 512 + lc, &Bs[0][rowb * 64]);
  }
  __syncthreads();

  for (int t = 0; t < 8; ++t) {
    const int cur = t & 1;
    if (t < 7) {
      const int k1 = (t + 1) * 64;
#pragma unroll
      for (int p = 0; p < 4; ++p) {
        const int rowb = w * 32 + p * 8;
        GLDS16(A + (size_t)(m0 + rowb + lr) * 512 + k1 + lc,
               &As[cur ^ 1][rowb * 64]);
        GLDS16(Bt + (size_t)(n0 + rowb + lr) * 512 + k1 + lc,
               &Bs[cur ^ 1][rowb * 64]);
      }
    }
#pragma unroll
    for (int ks = 0; ks < 2; ++ks) {
      bf16x8 af[4], bfr[4];
#pragma unroll
      for (int m = 0; m < 4; ++m)
        af[m] = *(bf16x8*)&As[cur][(wm * 64 + m * 16 + l16) * 64 + ks * 32 + quad * 8];
#pragma unroll
      for (int n = 0; n < 4; ++n)
        bfr[n] = *(bf16x8*)&Bs[cur][(wn * 64 + n * 16 + l16) * 64 + ks * 32 + quad * 8];
#pragma unroll
      for (int m = 0; m < 4; ++m)
#pragma unroll
        for (int n = 0; n < 4; ++n)
          acc[m][n] = __builtin_amdgcn_mfma_f32_16x16x32_bf16(af[m], bfr[n],
                                                              acc[m][n], 0, 0, 0);
    }
    if (t < 7) __syncthreads();
  }

#pragma unroll
  for (int m = 0; m < 4; ++m)
#pragma unroll
    for (int n = 0; n < 4; ++n) {
      const int col = n0 + wn * 64 + n * 16 + l16;
      const int rowb = m0 + wm * 64 + m * 16 + quad * 4;
      const float badd = bias[col];
#pragma unroll
      for (int r = 0; r < 4; ++r)
        C[(size_t)(rowb + r) * 512 + col] = acc[m][n][r] + badd;
    }
}

extern "C" void kernel_launch(void* const* d_in, const int* in_sizes, int n_in,
                              void* d_out, int out_size, void* d_ws, size_t ws_size,
                              hipStream_t stream) {
  const float* x   = (const float*)d_in[0];
  const float* ctx = (const float*)d_in[1];
  const float* Wq  = (const float*)d_in[2];
  const float* Wk  = (const float*)d_in[3];
  const float* Wv  = (const float*)d_in[4];
  const float* Wo  = (const float*)d_in[5];
  const float* bo  = (const float*)d_in[6];
  float* out = (float*)d_out;

  char* ws = (char*)d_ws;
  size_t off = 0;
  short* wqt = (short*)(ws + off); off += 512 * 512 * 2;
  short* wkt = (short*)(ws + off); off += 768 * 512 * 2;
  short* wvt = (short*)(ws + off); off += 768 * 512 * 2;
  short* wot = (short*)(ws + off); off += 512 * 512 * 2;
  short* Kb  = (short*)(ws + off); off += 1232 * 512 * 2;
  short* Vtg = (short*)(ws + off); off += (size_t)16 * 8 * 64 * 104 * 2;
  short* AOb = (short*)(ws + off); off += (size_t)65536 * 512 * 2;

  // all weight transposes + Vtg zero-fill in one dispatch
  prep_all<<<dim3(8, 12, 5), 256, 0, stream>>>(Wq, Wk, Wv, Wo,
                                               wqt, wkt, wvt, wot,
                                               (float4v*)Vtg);
  // K and V projections in one dispatch
  kvproj<<<dim3(4, 39, 2), 256, 0, stream>>>(ctx, wkt, wvt, Kb, Vtg);

  // fused Q-proj + attention -> AOb bf16
  qattn<<<512, 1024, 0, stream>>>(x, wqt, Kb, Vtg, AOb);

  // output projection + bias -> f32 d_out
  gemm2<<<2048, 256, 0, stream>>>(AOb, wot, out, bo);
}

// Round 15
// 183.984 us; speedup vs baseline: 1.0311x; 1.0311x over previous
//
#include <hip/hip_runtime.h>
#include <hip/hip_bf16.h>
#include <stdint.h>

// CrossAttention: out = softmax((x@Wq)(ctx@Wk)^T * scale) @ (ctx@Wv) @ Wo + bo
// B=16, NQ=4096, NK=77, QD=512, CD=768, H=8, DH=64, INNER=512
//
// Round 15: single isolated change vs round 14 — gemm2 (O-proj) moves from
// BK=64 dbuf (64 KB LDS, 2 blocks/CU = 8 waves/CU) to BK=32 dbuf (32 KB LDS,
// 4 blocks/CU = 16 waves/CU). Mechanism: independent blocks interleave at
// barriers (m114 wave-level overlap), hiding the 2-phase stage stall that a
// thin-occupancy layout exposes. Round 14's Vt-stride null confirmed the
// bank-conflict counter is intrinsic b128 aliasing, not a removable stall.

typedef __attribute__((ext_vector_type(8))) short bf16x8;
typedef __attribute__((ext_vector_type(4))) float f32x4;
typedef __attribute__((ext_vector_type(4))) short short4v;
typedef __attribute__((ext_vector_type(4))) float float4v;
typedef __attribute__((ext_vector_type(2))) unsigned uint2v;
typedef __attribute__((ext_vector_type(4))) unsigned uint4v;

#define DEVINL __device__ __forceinline__

DEVINL short f2bf(float f) {
  unsigned u = __builtin_bit_cast(unsigned, f);
  unsigned r = (u + 0x7FFFu + ((u >> 16) & 1u)) >> 16;  // RNE
  return (short)(unsigned short)r;
}

// packed f32x2 -> bf16x2 (RTNE), single VALU op
DEVINL unsigned pkbf(float lo, float hi) {
  unsigned r;
  asm("v_cvt_pk_bf16_f32 %0, %1, %2" : "=v"(r) : "v"(lo), "v"(hi));
  return r;
}

#define GLDS16(gp, sp)                                                \
  __builtin_amdgcn_global_load_lds(                                   \
      (const __attribute__((address_space(1))) void*)(gp),            \
      (__attribute__((address_space(3))) void*)(sp), 16, 0, 0)

// ---------------- batched prep: 4x weight transpose + Vtg zero-fill --------
// grid (8, 12, 5). z=0..3: W[K][512] f32 -> Wt[512][K] bf16 (kt guard).
// z=4: zero-fill Vtg (106496 float4 granules, grid-stride).
__global__ __launch_bounds__(256) void prep_all(
    const float* __restrict__ Wq, const float* __restrict__ Wk,
    const float* __restrict__ Wv, const float* __restrict__ Wo,
    short* __restrict__ wqt, short* __restrict__ wkt,
    short* __restrict__ wvt, short* __restrict__ wot,
    float4v* __restrict__ vfill) {
  const int z = blockIdx.z;
  if (z == 4) {
    for (int i = (blockIdx.y * 8 + blockIdx.x) * 256 + threadIdx.x;
         i < 106496; i += 24576)
      vfill[i] = float4v{0.f, 0.f, 0.f, 0.f};
    return;
  }
  const float* W;
  short* Wt;
  int K;
  switch (z) {
    case 0: W = Wq; Wt = wqt; K = 512; break;
    case 1: W = Wk; Wt = wkt; K = 768; break;
    case 2: W = Wv; Wt = wvt; K = 768; break;
    default: W = Wo; Wt = wot; K = 512; break;
  }
  const int kt = blockIdx.y * 64;
  if (kt >= K) return;
  const int nt = blockIdx.x * 64;

  __shared__ short Tl[64][65];
#pragma unroll
  for (int i = 0; i < 16; ++i) {
    int idx = threadIdx.x + i * 256;
    int r = idx >> 6, c = idx & 63;
    Tl[c][r] = f2bf(W[(size_t)(kt + r) * 512 + nt + c]);
  }
  __syncthreads();
#pragma unroll
  for (int i = 0; i < 16; ++i) {
    int idx = threadIdx.x + i * 256;
    int r = idx >> 6, c = idx & 63;
    Wt[(size_t)(nt + r) * K + kt + c] = Tl[r][c];
  }
}

// ---------------- K+V projections in one dispatch ---------------------------
// grid (4, 39, 2). z=0: Kb[M][512] bf16 = ctx @ wkt^T.
// z=1: V scatter -> Vtg[((b*8+h)*64+d)*104 + key] (pads pre-zeroed).
__global__ __launch_bounds__(256) void kvproj(const float* __restrict__ A,
                                              const short* __restrict__ wkt,
                                              const short* __restrict__ wvt,
                                              short* __restrict__ Kb,
                                              short* __restrict__ Vtg) {
  __shared__ short Al[32][40];
  __shared__ short Bl[128][40];

  const int TRANS = blockIdx.z;
  const short* Bt = TRANS ? wvt : wkt;

  const int tid = threadIdx.x;
  const int lane = tid & 63, wid = tid >> 6;
  const int wm = wid >> 1, wn = wid & 1;
  const int quad = lane >> 4, l16 = lane & 15;
  const int m0 = blockIdx.y * 32, n0 = blockIdx.x * 128;
  const int M = 1232, K = 768;

  f32x4 acc[4] = {};

  for (int k0 = 0; k0 < K; k0 += 32) {
    for (int idx = tid; idx < 32 * 8; idx += 256) {
      int row = idx >> 3, kq = idx & 7;
      float4v v = {};
      if (m0 + row < M)
        v = *(const float4v*)(A + (size_t)(m0 + row) * K + k0 + kq * 4);
      short4v s = {f2bf(v[0]), f2bf(v[1]), f2bf(v[2]), f2bf(v[3])};
      *(short4v*)&Al[row][kq * 4] = s;
    }
    for (int idx = tid; idx < 512; idx += 256) {
      int row = idx >> 2, kq = idx & 3;
      *(bf16x8*)&Bl[row][kq * 8] =
          *(const bf16x8*)(Bt + (size_t)(n0 + row) * K + k0 + kq * 8);
    }
    __syncthreads();

    bf16x8 a = *(bf16x8*)&Al[wm * 16 + l16][quad * 8];
#pragma unroll
    for (int n = 0; n < 4; ++n) {
      bf16x8 b = *(bf16x8*)&Bl[wn * 64 + n * 16 + l16][quad * 8];
      acc[n] = __builtin_amdgcn_mfma_f32_16x16x32_bf16(a, b, acc[n], 0, 0, 0);
    }
    __syncthreads();
  }

#pragma unroll
  for (int n = 0; n < 4; ++n) {
    const int col = n0 + wn * 64 + n * 16 + l16;
    const int rowb = m0 + wm * 16 + quad * 4;
#pragma unroll
    for (int r = 0; r < 4; ++r) {
      const int rr = rowb + r;
      if (rr < M) {
        if (!TRANS) {
          Kb[(size_t)rr * 512 + col] = f2bf(acc[n][r]);
        } else {
          const int bb = rr / 77, key = rr - bb * 77;
          Vtg[(size_t)((bb * 8 + (col >> 6)) * 64 + (col & 63)) * 104 + key] =
              f2bf(acc[n][r]);
        }
      }
    }
  }
}

// ---------------- fused Q-proj + attention ---------------------------------
// 1024 thr (16 waves). Phase 1: BK=32, 16 steps, LDS double-buffer
// (xb[2][128][40], wsW[2][512][40]), reg-staged, prefetch after barrier,
// ONE __syncthreads per step. Phase 2: 4 iters x 2 heads; Vt stride 104.
__global__ __launch_bounds__(1024, 4) void qattn(const float* __restrict__ x,
                                                 const short* __restrict__ wqt,
                                                 const short* __restrict__ Kb,
                                                 const short* __restrict__ Vtg,
                                                 short* __restrict__ AOb) {
  __shared__ __align__(16) char smem[127488];
  short* xb  = (short*)smem;               // ph1: [2][128][40] bf16, 20480 B
  short* wsW = (short*)(smem + 20480);     // ph1: [2][512][40] bf16, 81920 B
  short* Qh  = (short*)smem;               // ph2: [2][128][72], 36864 B
  short* Kl  = (short*)(smem + 36864);     // ph2: [2][80][72], 23040 B
  short* Vt  = (short*)(smem + 59904);     // ph2: [2][64][104], 26624 B
  short* Pw  = (short*)(smem + 86528);     // ph2: [16][16][80], 40960 B

  const int tid = threadIdx.x;
  const int lane = tid & 63, w = tid >> 6;
  const int wm = w >> 3, wn = w & 7;
  const int quad = lane >> 4, l16 = lane & 15;
  const int m0 = blockIdx.x * 128;
  const int b = m0 >> 12;

  f32x4 acc[4][4] = {};

  // ============ phase 1: Q projection, BK=32 pipelined (16 steps) ==========
  const int xrow = tid >> 3, xcol = (tid & 7) * 4;
  const int wr0 = tid >> 2, wc0 = (tid & 3) * 8;
  const int wr1 = (tid + 1024) >> 2, wc1 = wc0;

  const float* xg = x + (size_t)(m0 + xrow) * 512 + xcol;
  const short* wg0 = wqt + (size_t)wr0 * 512 + wc0;
  const short* wg1 = wqt + (size_t)wr1 * 512 + wc1;

  float4v px;
  bf16x8 pw0, pw1;
  px = *(const float4v*)(xg);
  pw0 = *(const bf16x8*)(wg0);
  pw1 = *(const bf16x8*)(wg1);

  for (int t = 0; t < 16; ++t) {
    short* xbuf = xb + (t & 1) * 5120;
    short* wbuf = wsW + (t & 1) * 20480;

    *(uint2v*)&xbuf[xrow * 40 + xcol] =
        uint2v{pkbf(px[0], px[1]), pkbf(px[2], px[3])};
    *(bf16x8*)&wbuf[wr0 * 40 + wc0] = pw0;
    *(bf16x8*)&wbuf[wr1 * 40 + wc1] = pw1;

    __syncthreads();

    if (t < 15) {
      const int k1 = (t + 1) * 32;
      px = *(const float4v*)(xg + k1);
      pw0 = *(const bf16x8*)(wg0 + k1);
      pw1 = *(const bf16x8*)(wg1 + k1);
    }

    bf16x8 af[4], bfr[4];
#pragma unroll
    for (int m = 0; m < 4; ++m)
      af[m] = *(bf16x8*)&xbuf[(wm * 64 + m * 16 + l16) * 40 + quad * 8];
#pragma unroll
    for (int n = 0; n < 4; ++n)
      bfr[n] = *(bf16x8*)&wbuf[(wn * 64 + n * 16 + l16) * 40 + quad * 8];
#pragma unroll
    for (int m = 0; m < 4; ++m)
#pragma unroll
      for (int n = 0; n < 4; ++n)
        acc[m][n] = __builtin_amdgcn_mfma_f32_16x16x32_bf16(af[m], bfr[n],
                                                            acc[m][n], 0, 0, 0);
  }
  __syncthreads();

  // ================= phase 2: 4 iters x 2 heads =================
#pragma unroll
  for (int it = 0; it < 4; ++it) {
    if (it) __syncthreads();

    if ((wn >> 1) == it) {
      const int slot = wn & 1;
#pragma unroll
      for (int m = 0; m < 4; ++m)
#pragma unroll
        for (int n = 0; n < 4; ++n)
#pragma unroll
          for (int r = 0; r < 4; ++r)
            Qh[slot * 9216 + (wm * 64 + m * 16 + quad * 4 + r) * 72 +
               n * 16 + l16] = f2bf(acc[m][n][r]);
    }
    for (int idx = tid; idx < 1232; idx += 1024) {
      const int sk = idx >= 616;
      const int e = idx - sk * 616;
      const int r = e >> 3, cc = (e & 7) * 8;
      *(bf16x8*)&Kl[sk * 5760 + r * 72 + cc] =
          *(const bf16x8*)(Kb + ((size_t)b * 77 + r) * 512 +
                           (it * 2 + sk) * 64 + cc);
    }
    // V^T stage x2 heads, linear GLDS: 13 chunks of 1 KB per head
    for (int cid = w; cid < 26; cid += 16) {
      const int sv = cid >= 13;
      const int c13 = cid - sv * 13;
      GLDS16(Vtg + (size_t)(b * 8 + it * 2 + sv) * 6656 + c13 * 512 + lane * 8,
             Vt + sv * 6656 + c13 * 512);
    }
    __syncthreads();

    bf16x8 qfr[2];
#pragma unroll
    for (int ks = 0; ks < 2; ++ks)
      qfr[ks] = *(bf16x8*)&Qh[wm * 9216 + (wn * 16 + l16) * 72 +
                              ks * 32 + quad * 8];

    f32x4 c[5] = {};
#pragma unroll
    for (int f = 0; f < 5; ++f)
#pragma unroll
      for (int ks = 0; ks < 2; ++ks) {
        bf16x8 a = *(bf16x8*)&Kl[wm * 5760 + (f * 16 + l16) * 72 +
                                 ks * 32 + quad * 8];
        c[f] = __builtin_amdgcn_mfma_f32_16x16x32_bf16(a, qfr[ks], c[f], 0, 0, 0);
      }

    float mx = -1e30f;
#pragma unroll
    for (int f = 0; f < 5; ++f)
#pragma unroll
      for (int r = 0; r < 4; ++r) {
        const int key = f * 16 + quad * 4 + r;
        float v = c[f][r] * 0.125f;
        v = (key < 77) ? v : -1e30f;
        c[f][r] = v;
        mx = fmaxf(mx, v);
      }
    mx = fmaxf(mx, __shfl_xor(mx, 16));
    mx = fmaxf(mx, __shfl_xor(mx, 32));

    short* pbase = Pw + (w * 16 + l16) * 80;
    float sum = 0.f;
#pragma unroll
    for (int f = 0; f < 5; ++f) {
      float e0 = __expf(c[f][0] - mx), e1 = __expf(c[f][1] - mx);
      float e2 = __expf(c[f][2] - mx), e3 = __expf(c[f][3] - mx);
      sum += (e0 + e1) + (e2 + e3);
      uint2v sv2 = {pkbf(e0, e1), pkbf(e2, e3)};
      *(uint2v*)(pbase + f * 16 + quad * 4) = sv2;
    }
    sum += __shfl_xor(sum, 16);
    sum += __shfl_xor(sum, 32);
    const float inv = 1.0f / sum;

    bf16x8 pb0 = *(bf16x8*)(pbase + quad * 8);
    bf16x8 pb1 = *(bf16x8*)(pbase + 32 + quad * 8);
    bf16x8 pb2 = bf16x8{0, 0, 0, 0, 0, 0, 0, 0};
    if (quad < 2) pb2 = *(bf16x8*)(pbase + 64 + quad * 8);

    f32x4 o[4] = {};
#pragma unroll
    for (int mt = 0; mt < 4; ++mt) {
      const short* vrow = &Vt[wm * 6656 + (mt * 16 + l16) * 104];
      o[mt] = __builtin_amdgcn_mfma_f32_16x16x32_bf16(
          *(bf16x8*)(vrow + quad * 8), pb0, o[mt], 0, 0, 0);
      o[mt] = __builtin_amdgcn_mfma_f32_16x16x32_bf16(
          *(bf16x8*)(vrow + 32 + quad * 8), pb1, o[mt], 0, 0, 0);
      o[mt] = __builtin_amdgcn_mfma_f32_16x16x32_bf16(
          *(bf16x8*)(vrow + 64 + quad * 8), pb2, o[mt], 0, 0, 0);
    }

    short* op = AOb + ((size_t)m0 + wn * 16 + l16) * 512 + (it * 2 + wm) * 64;
#pragma unroll
    for (int mt = 0; mt < 4; ++mt) {
      uint2v sv2 = {pkbf(o[mt][0] * inv, o[mt][1] * inv),
                    pkbf(o[mt][2] * inv, o[mt][3] * inv)};
      *(uint2v*)(op + mt * 16 + quad * 4) = sv2;
    }
  }
}

// ---------------- O-proj: 2-phase dbuf GEMM, bf16 A/B, BK=32 ---------------
// C[M][512] f32+bias = A[M][512]bf16 @ Bt[512][512]bf16^T. 128x128 tile,
// BK=32, 16 steps, 4 waves, 32 KB LDS -> 4 blocks/CU (16 waves/CU), so
// independent blocks interleave at barriers and hide the per-step stall.
__global__ __launch_bounds__(256) void gemm2(const short* __restrict__ A,
                                             const short* __restrict__ Bt,
                                             float* __restrict__ C,
                                             const float* __restrict__ bias) {
  __shared__ short As[2][128 * 32];  // 2 x 8 KB
  __shared__ short Bs[2][128 * 32];  // 2 x 8 KB

  const int tid = threadIdx.x;
  const int lane = tid & 63, w = tid >> 6;
  const int wm = w >> 1, wn = w & 1;
  const int quad = lane >> 4, l16 = lane & 15;

  const int cpx = gridDim.x >> 3;
  const int swz = (blockIdx.x & 7) * cpx + (blockIdx.x >> 3);
  const int m0 = (swz >> 2) * 128, n0 = (swz & 3) * 128;

  // staging: 1 KB chunk = 16 rows x 32 bf16; lane -> row lane>>2, col (lane&3)*8
  const int lr = lane >> 2, lc = (lane & 3) * 8;

  f32x4 acc[4][4] = {};

  // prologue: stage tile 0 (per wave: 2 A-chunks + 2 B-chunks)
#pragma unroll
  for (int p = 0; p < 2; ++p) {
    const int rowb = (w * 2 + p) * 16;
    GLDS16(A + (size_t)(m0 + rowb + lr) * 512 + lc, &As[0][rowb * 32]);
    GLDS16(Bt + (size_t)(n0 + rowb + lr) * 512 + lc, &Bs[0][rowb * 32]);
  }
  __syncthreads();

  for (int t = 0; t < 16; ++t) {
    const int cur = t & 1;
    if (t < 15) {
      const int k1 = (t + 1) * 32;
#pragma unroll
      for (int p = 0; p < 2; ++p) {
        const int rowb = (w * 2 + p) * 16;
        GLDS16(A + (size_t)(m0 + rowb + lr) * 512 + k1 + lc,
               &As[cur ^ 1][rowb * 32]);
        GLDS16(Bt + (size_t)(n0 + rowb + lr) * 512 + k1 + lc,
               &Bs[cur ^ 1][rowb * 32]);
      }
    }
    bf16x8 af[4], bfr[4];
#pragma unroll
    for (int m = 0; m < 4; ++m)
      af[m] = *(bf16x8*)&As[cur][(wm * 64 + m * 16 + l16) * 32 + quad * 8];
#pragma unroll
    for (int n = 0; n < 4; ++n)
      bfr[n] = *(bf16x8*)&Bs[cur][(wn * 64 + n * 16 + l16) * 32 + quad * 8];
#pragma unroll
    for (int m = 0; m < 4; ++m)
#pragma unroll
      for (int n = 0; n < 4; ++n)
        acc[m][n] = __builtin_amdgcn_mfma_f32_16x16x32_bf16(af[m], bfr[n],
                                                            acc[m][n], 0, 0, 0);
    if (t < 15) __syncthreads();
  }

#pragma unroll
  for (int m = 0; m < 4; ++m)
#pragma unroll
    for (int n = 0; n < 4; ++n) {
      const int col = n0 + wn * 64 + n * 16 + l16;
      const int rowb = m0 + wm * 64 + m * 16 + quad * 4;
      const float badd = bias[col];
#pragma unroll
      for (int r = 0; r < 4; ++r)
        C[(size_t)(rowb + r) * 512 + col] = acc[m][n][r] + badd;
    }
}

extern "C" void kernel_launch(void* const* d_in, const int* in_sizes, int n_in,
                              void* d_out, int out_size, void* d_ws, size_t ws_size,
                              hipStream_t stream) {
  const float* x   = (const float*)d_in[0];
  const float* ctx = (const float*)d_in[1];
  const float* Wq  = (const float*)d_in[2];
  const float* Wk  = (const float*)d_in[3];
  const float* Wv  = (const float*)d_in[4];
  const float* Wo  = (const float*)d_in[5];
  const float* bo  = (const float*)d_in[6];
  float* out = (float*)d_out;

  char* ws = (char*)d_ws;
  size_t off = 0;
  short* wqt = (short*)(ws + off); off += 512 * 512 * 2;
  short* wkt = (short*)(ws + off); off += 768 * 512 * 2;
  short* wvt = (short*)(ws + off); off += 768 * 512 * 2;
  short* wot = (short*)(ws + off); off += 512 * 512 * 2;
  short* Kb  = (short*)(ws + off); off += 1232 * 512 * 2;
  short* Vtg = (short*)(ws + off); off += (size_t)16 * 8 * 64 * 104 * 2;
  short* AOb = (short*)(ws + off); off += (size_t)65536 * 512 * 2;

  // all weight transposes + Vtg zero-fill in one dispatch
  prep_all<<<dim3(8, 12, 5), 256, 0, stream>>>(Wq, Wk, Wv, Wo,
                                               wqt, wkt, wvt, wot,
                                               (float4v*)Vtg);
  // K and V projections in one dispatch
  kvproj<<<dim3(4, 39, 2), 256, 0, stream>>>(ctx, wkt, wvt, Kb, Vtg);

  // fused Q-proj + attention -> AOb bf16
  qattn<<<512, 1024, 0, stream>>>(x, wqt, Kb, Vtg, AOb);

  // output projection + bias -> f32 d_out
  gemm2<<<2048, 256, 0, stream>>>(AOb, wot, out, bo);
}

// Round 16
// 179.949 us; speedup vs baseline: 1.0542x; 1.0224x over previous
//
#include <hip/hip_runtime.h>
#include <hip/hip_bf16.h>
#include <stdint.h>

// CrossAttention: out = softmax((x@Wq)(ctx@Wk)^T * scale) @ (ctx@Wv) @ Wo + bo
// B=16, NQ=4096, NK=77, QD=512, CD=768, H=8, DH=64, INNER=512
//
// Round 16: qattn split into 8-wave blocks over half the heads each.
// Block = 128 q-rows x 256 cols (4 heads); LDS 63744 B -> 2 blocks/CU,
// giving two independent barrier domains per CU (the round-15 gemm2 lever).
// Same math as round-9 qattn: phase-1 reg-staged BK=32 pipeline (wsW
// halved), phase-2 4 iters x 1 head. x is read twice (HBM slack at 9%).

typedef __attribute__((ext_vector_type(8))) short bf16x8;
typedef __attribute__((ext_vector_type(4))) float f32x4;
typedef __attribute__((ext_vector_type(4))) short short4v;
typedef __attribute__((ext_vector_type(4))) float float4v;
typedef __attribute__((ext_vector_type(2))) unsigned uint2v;
typedef __attribute__((ext_vector_type(4))) unsigned uint4v;

#define DEVINL __device__ __forceinline__

DEVINL short f2bf(float f) {
  unsigned u = __builtin_bit_cast(unsigned, f);
  unsigned r = (u + 0x7FFFu + ((u >> 16) & 1u)) >> 16;  // RNE
  return (short)(unsigned short)r;
}

// packed f32x2 -> bf16x2 (RTNE), single VALU op
DEVINL unsigned pkbf(float lo, float hi) {
  unsigned r;
  asm("v_cvt_pk_bf16_f32 %0, %1, %2" : "=v"(r) : "v"(lo), "v"(hi));
  return r;
}

#define GLDS16(gp, sp)                                                \
  __builtin_amdgcn_global_load_lds(                                   \
      (const __attribute__((address_space(1))) void*)(gp),            \
      (__attribute__((address_space(3))) void*)(sp), 16, 0, 0)

// ---------------- batched prep: 4x weight transpose + Vtg zero-fill --------
__global__ __launch_bounds__(256) void prep_all(
    const float* __restrict__ Wq, const float* __restrict__ Wk,
    const float* __restrict__ Wv, const float* __restrict__ Wo,
    short* __restrict__ wqt, short* __restrict__ wkt,
    short* __restrict__ wvt, short* __restrict__ wot,
    float4v* __restrict__ vfill) {
  const int z = blockIdx.z;
  if (z == 4) {
    for (int i = (blockIdx.y * 8 + blockIdx.x) * 256 + threadIdx.x;
         i < 106496; i += 24576)
      vfill[i] = float4v{0.f, 0.f, 0.f, 0.f};
    return;
  }
  const float* W;
  short* Wt;
  int K;
  switch (z) {
    case 0: W = Wq; Wt = wqt; K = 512; break;
    case 1: W = Wk; Wt = wkt; K = 768; break;
    case 2: W = Wv; Wt = wvt; K = 768; break;
    default: W = Wo; Wt = wot; K = 512; break;
  }
  const int kt = blockIdx.y * 64;
  if (kt >= K) return;
  const int nt = blockIdx.x * 64;

  __shared__ short Tl[64][65];
#pragma unroll
  for (int i = 0; i < 16; ++i) {
    int idx = threadIdx.x + i * 256;
    int r = idx >> 6, c = idx & 63;
    Tl[c][r] = f2bf(W[(size_t)(kt + r) * 512 + nt + c]);
  }
  __syncthreads();
#pragma unroll
  for (int i = 0; i < 16; ++i) {
    int idx = threadIdx.x + i * 256;
    int r = idx >> 6, c = idx & 63;
    Wt[(size_t)(nt + r) * K + kt + c] = Tl[r][c];
  }
}

// ---------------- K+V projections in one dispatch ---------------------------
__global__ __launch_bounds__(256) void kvproj(const float* __restrict__ A,
                                              const short* __restrict__ wkt,
                                              const short* __restrict__ wvt,
                                              short* __restrict__ Kb,
                                              short* __restrict__ Vtg) {
  __shared__ short Al[32][40];
  __shared__ short Bl[128][40];

  const int TRANS = blockIdx.z;
  const short* Bt = TRANS ? wvt : wkt;

  const int tid = threadIdx.x;
  const int lane = tid & 63, wid = tid >> 6;
  const int wm = wid >> 1, wn = wid & 1;
  const int quad = lane >> 4, l16 = lane & 15;
  const int m0 = blockIdx.y * 32, n0 = blockIdx.x * 128;
  const int M = 1232, K = 768;

  f32x4 acc[4] = {};

  for (int k0 = 0; k0 < K; k0 += 32) {
    for (int idx = tid; idx < 32 * 8; idx += 256) {
      int row = idx >> 3, kq = idx & 7;
      float4v v = {};
      if (m0 + row < M)
        v = *(const float4v*)(A + (size_t)(m0 + row) * K + k0 + kq * 4);
      short4v s = {f2bf(v[0]), f2bf(v[1]), f2bf(v[2]), f2bf(v[3])};
      *(short4v*)&Al[row][kq * 4] = s;
    }
    for (int idx = tid; idx < 512; idx += 256) {
      int row = idx >> 2, kq = idx & 3;
      *(bf16x8*)&Bl[row][kq * 8] =
          *(const bf16x8*)(Bt + (size_t)(n0 + row) * K + k0 + kq * 8);
    }
    __syncthreads();

    bf16x8 a = *(bf16x8*)&Al[wm * 16 + l16][quad * 8];
#pragma unroll
    for (int n = 0; n < 4; ++n) {
      bf16x8 b = *(bf16x8*)&Bl[wn * 64 + n * 16 + l16][quad * 8];
      acc[n] = __builtin_amdgcn_mfma_f32_16x16x32_bf16(a, b, acc[n], 0, 0, 0);
    }
    __syncthreads();
  }

#pragma unroll
  for (int n = 0; n < 4; ++n) {
    const int col = n0 + wn * 64 + n * 16 + l16;
    const int rowb = m0 + wm * 16 + quad * 4;
#pragma unroll
    for (int r = 0; r < 4; ++r) {
      const int rr = rowb + r;
      if (rr < M) {
        if (!TRANS) {
          Kb[(size_t)rr * 512 + col] = f2bf(acc[n][r]);
        } else {
          const int bb = rr / 77, key = rr - bb * 77;
          Vtg[(size_t)((bb * 8 + (col >> 6)) * 64 + (col & 63)) * 104 + key] =
              f2bf(acc[n][r]);
        }
      }
    }
  }
}

// ---------------- fused Q-proj + attention, 8-wave half-head blocks --------
// 512 thr (8 waves), grid 1024: qt = bx & 511 (128 q-rows), ch = bx >> 9
// (heads 4ch..4ch+3). Phase 1: wave grid 2x4 (wm rows, wn cols), tile 64x64,
// BK=32 x16 steps, reg-staged dbuf, 1 barrier/step. Phase 2: 4 iters x 1
// head; each wave does 16 q-rows. LDS 63744 B -> 2 blocks/CU.
__global__ __launch_bounds__(512, 4) void qattn(const float* __restrict__ x,
                                                const short* __restrict__ wqt,
                                                const short* __restrict__ Kb,
                                                const short* __restrict__ Vtg,
                                                short* __restrict__ AOb) {
  __shared__ __align__(16) char smem[63744];
  short* xb  = (short*)smem;               // ph1: [2][128][40] bf16, 20480 B
  short* wsW = (short*)(smem + 20480);     // ph1: [2][256][40] bf16, 40960 B
  short* Qh  = (short*)smem;               // ph2: [128][72], 18432 B
  short* Kl  = (short*)(smem + 18432);     // ph2: [80][72], 11520 B
  short* Vt  = (short*)(smem + 29952);     // ph2: [64][104], 13312 B
  short* Pw  = (short*)(smem + 43264);     // ph2: [8][16][80], 20480 B

  const int tid = threadIdx.x;
  const int lane = tid & 63, w = tid >> 6;
  const int wm = w >> 2, wn = w & 3;       // phase-1 wave grid 2x4
  const int quad = lane >> 4, l16 = lane & 15;
  const int qt = blockIdx.x & 511, ch = blockIdx.x >> 9;
  const int m0 = qt * 128;
  const int b = qt >> 5;
  const int n0 = ch * 256;                 // wqt row base (heads 4ch..4ch+3)

  f32x4 acc[4][4] = {};

  // ============ phase 1: Q-proj (128 x 256), BK=32 pipelined ==========
  const int xrow = tid >> 2, xcol = (tid & 3) * 8;   // x: 8 f32/thread
  const int wr = tid >> 1, wc = (tid & 1) * 16;      // wqt: 16 bf16/thread

  const float* xg = x + (size_t)(m0 + xrow) * 512 + xcol;
  const short* wg = wqt + (size_t)(n0 + wr) * 512 + wc;

  float4v pxa, pxb;
  bf16x8 pw0, pw1;
  pxa = *(const float4v*)(xg);
  pxb = *(const float4v*)(xg + 4);
  pw0 = *(const bf16x8*)(wg);
  pw1 = *(const bf16x8*)(wg + 8);

  for (int t = 0; t < 16; ++t) {
    short* xbuf = xb + (t & 1) * 5120;     // 128*40
    short* wbuf = wsW + (t & 1) * 10240;   // 256*40

    uint4v u = {pkbf(pxa[0], pxa[1]), pkbf(pxa[2], pxa[3]),
                pkbf(pxb[0], pxb[1]), pkbf(pxb[2], pxb[3])};
    *(bf16x8*)&xbuf[xrow * 40 + xcol] = __builtin_bit_cast(bf16x8, u);
    *(bf16x8*)&wbuf[wr * 40 + wc] = pw0;
    *(bf16x8*)&wbuf[wr * 40 + wc + 8] = pw1;

    __syncthreads();

    if (t < 15) {
      const int k1 = (t + 1) * 32;
      pxa = *(const float4v*)(xg + k1);
      pxb = *(const float4v*)(xg + k1 + 4);
      pw0 = *(const bf16x8*)(wg + k1);
      pw1 = *(const bf16x8*)(wg + k1 + 8);
    }

    bf16x8 af[4], bfr[4];
#pragma unroll
    for (int m = 0; m < 4; ++m)
      af[m] = *(bf16x8*)&xbuf[(wm * 64 + m * 16 + l16) * 40 + quad * 8];
#pragma unroll
    for (int n = 0; n < 4; ++n)
      bfr[n] = *(bf16x8*)&wbuf[(wn * 64 + n * 16 + l16) * 40 + quad * 8];
#pragma unroll
    for (int m = 0; m < 4; ++m)
#pragma unroll
      for (int n = 0; n < 4; ++n)
        acc[m][n] = __builtin_amdgcn_mfma_f32_16x16x32_bf16(af[m], bfr[n],
                                                            acc[m][n], 0, 0, 0);
  }
  __syncthreads();  // phase-1 reads done before phase-2 overlay writes

  // ================= phase 2: 4 iters x 1 head =================
#pragma unroll
  for (int it = 0; it < 4; ++it) {
    if (it) __syncthreads();
    const int h = ch * 4 + it;

    // (a) Q dump: the 2 waves with wn == it own head it's columns
    if (wn == it) {
#pragma unroll
      for (int m = 0; m < 4; ++m)
#pragma unroll
        for (int n = 0; n < 4; ++n)
#pragma unroll
          for (int r = 0; r < 4; ++r)
            Qh[(wm * 64 + m * 16 + quad * 4 + r) * 72 + n * 16 + l16] =
                f2bf(acc[m][n][r]);
    }
    // (b) K stage (rows 0..76; 77..79 garbage -> masked)
    for (int idx = tid; idx < 616; idx += 512) {
      const int r = idx >> 3, cc = (idx & 7) * 8;
      *(bf16x8*)&Kl[r * 72 + cc] =
          *(const bf16x8*)(Kb + ((size_t)b * 77 + r) * 512 + h * 64 + cc);
    }
    // (c) V^T stage, linear GLDS: 13 chunks of 1 KB
    for (int cid = w; cid < 13; cid += 8)
      GLDS16(Vtg + (size_t)(b * 8 + h) * 6656 + cid * 512 + lane * 8,
             Vt + cid * 512);
    __syncthreads();

    // (d) attention: q rows w*16..+15
    bf16x8 qfr[2];
#pragma unroll
    for (int ks = 0; ks < 2; ++ks)
      qfr[ks] = *(bf16x8*)&Qh[(w * 16 + l16) * 72 + ks * 32 + quad * 8];

    f32x4 c[5] = {};
#pragma unroll
    for (int f = 0; f < 5; ++f)
#pragma unroll
      for (int ks = 0; ks < 2; ++ks) {
        bf16x8 a = *(bf16x8*)&Kl[(f * 16 + l16) * 72 + ks * 32 + quad * 8];
        c[f] = __builtin_amdgcn_mfma_f32_16x16x32_bf16(a, qfr[ks], c[f], 0, 0, 0);
      }

    float mx = -1e30f;
#pragma unroll
    for (int f = 0; f < 5; ++f)
#pragma unroll
      for (int r = 0; r < 4; ++r) {
        const int key = f * 16 + quad * 4 + r;
        float v = c[f][r] * 0.125f;
        v = (key < 77) ? v : -1e30f;
        c[f][r] = v;
        mx = fmaxf(mx, v);
      }
    mx = fmaxf(mx, __shfl_xor(mx, 16));
    mx = fmaxf(mx, __shfl_xor(mx, 32));

    short* pbase = Pw + (w * 16 + l16) * 80;
    float sum = 0.f;
#pragma unroll
    for (int f = 0; f < 5; ++f) {
      float e0 = __expf(c[f][0] - mx), e1 = __expf(c[f][1] - mx);
      float e2 = __expf(c[f][2] - mx), e3 = __expf(c[f][3] - mx);
      sum += (e0 + e1) + (e2 + e3);
      uint2v sv2 = {pkbf(e0, e1), pkbf(e2, e3)};
      *(uint2v*)(pbase + f * 16 + quad * 4) = sv2;
    }
    sum += __shfl_xor(sum, 16);
    sum += __shfl_xor(sum, 32);
    const float inv = 1.0f / sum;

    bf16x8 pb0 = *(bf16x8*)(pbase + quad * 8);
    bf16x8 pb1 = *(bf16x8*)(pbase + 32 + quad * 8);
    bf16x8 pb2 = bf16x8{0, 0, 0, 0, 0, 0, 0, 0};
    if (quad < 2) pb2 = *(bf16x8*)(pbase + 64 + quad * 8);

    f32x4 o[4] = {};
#pragma unroll
    for (int mt = 0; mt < 4; ++mt) {
      const short* vrow = &Vt[(mt * 16 + l16) * 104];
      o[mt] = __builtin_amdgcn_mfma_f32_16x16x32_bf16(
          *(bf16x8*)(vrow + quad * 8), pb0, o[mt], 0, 0, 0);
      o[mt] = __builtin_amdgcn_mfma_f32_16x16x32_bf16(
          *(bf16x8*)(vrow + 32 + quad * 8), pb1, o[mt], 0, 0, 0);
      o[mt] = __builtin_amdgcn_mfma_f32_16x16x32_bf16(
          *(bf16x8*)(vrow + 64 + quad * 8), pb2, o[mt], 0, 0, 0);
    }

    short* op = AOb + ((size_t)m0 + w * 16 + l16) * 512 + h * 64;
#pragma unroll
    for (int mt = 0; mt < 4; ++mt) {
      uint2v sv2 = {pkbf(o[mt][0] * inv, o[mt][1] * inv),
                    pkbf(o[mt][2] * inv, o[mt][3] * inv)};
      *(uint2v*)(op + mt * 16 + quad * 4) = sv2;
    }
  }
}

// ---------------- O-proj: 2-phase dbuf GEMM, bf16 A/B, BK=32 ---------------
__global__ __launch_bounds__(256) void gemm2(const short* __restrict__ A,
                                             const short* __restrict__ Bt,
                                             float* __restrict__ C,
                                             const float* __restrict__ bias) {
  __shared__ short As[2][128 * 32];
  __shared__ short Bs[2][128 * 32];

  const int tid = threadIdx.x;
  const int lane = tid & 63, w = tid >> 6;
  const int wm = w >> 1, wn = w & 1;
  const int quad = lane >> 4, l16 = lane & 15;

  const int cpx = gridDim.x >> 3;
  const int swz = (blockIdx.x & 7) * cpx + (blockIdx.x >> 3);
  const int m0 = (swz >> 2) * 128, n0 = (swz & 3) * 128;

  const int lr = lane >> 2, lc = (lane & 3) * 8;

  f32x4 acc[4][4] = {};

#pragma unroll
  for (int p = 0; p < 2; ++p) {
    const int rowb = (w * 2 + p) * 16;
    GLDS16(A + (size_t)(m0 + rowb + lr) * 512 + lc, &As[0][rowb * 32]);
    GLDS16(Bt + (size_t)(n0 + rowb + lr) * 512 + lc, &Bs[0][rowb * 32]);
  }
  __syncthreads();

  for (int t = 0; t < 16; ++t) {
    const int cur = t & 1;
    if (t < 15) {
      const int k1 = (t + 1) * 32;
#pragma unroll
      for (int p = 0; p < 2; ++p) {
        const int rowb = (w * 2 + p) * 16;
        GLDS16(A + (size_t)(m0 + rowb + lr) * 512 + k1 + lc,
               &As[cur ^ 1][rowb * 32]);
        GLDS16(Bt + (size_t)(n0 + rowb + lr) * 512 + k1 + lc,
               &Bs[cur ^ 1][rowb * 32]);
      }
    }
    bf16x8 af[4], bfr[4];
#pragma unroll
    for (int m = 0; m < 4; ++m)
      af[m] = *(bf16x8*)&As[cur][(wm * 64 + m * 16 + l16) * 32 + quad * 8];
#pragma unroll
    for (int n = 0; n < 4; ++n)
      bfr[n] = *(bf16x8*)&Bs[cur][(wn * 64 + n * 16 + l16) * 32 + quad * 8];
#pragma unroll
    for (int m = 0; m < 4; ++m)
#pragma unroll
      for (int n = 0; n < 4; ++n)
        acc[m][n] = __builtin_amdgcn_mfma_f32_16x16x32_bf16(af[m], bfr[n],
                                                            acc[m][n], 0, 0, 0);
    if (t < 15) __syncthreads();
  }

#pragma unroll
  for (int m = 0; m < 4; ++m)
#pragma unroll
    for (int n = 0; n < 4; ++n) {
      const int col = n0 + wn * 64 + n * 16 + l16;
      const int rowb = m0 + wm * 64 + m * 16 + quad * 4;
      const float badd = bias[col];
#pragma unroll
      for (int r = 0; r < 4; ++r)
        C[(size_t)(rowb + r) * 512 + col] = acc[m][n][r] + badd;
    }
}

extern "C" void kernel_launch(void* const* d_in, const int* in_sizes, int n_in,
                              void* d_out, int out_size, void* d_ws, size_t ws_size,
                              hipStream_t stream) {
  const float* x   = (const float*)d_in[0];
  const float* ctx = (const float*)d_in[1];
  const float* Wq  = (const float*)d_in[2];
  const float* Wk  = (const float*)d_in[3];
  const float* Wv  = (const float*)d_in[4];
  const float* Wo  = (const float*)d_in[5];
  const float* bo  = (const float*)d_in[6];
  float* out = (float*)d_out;

  char* ws = (char*)d_ws;
  size_t off = 0;
  short* wqt = (short*)(ws + off); off += 512 * 512 * 2;
  short* wkt = (short*)(ws + off); off += 768 * 512 * 2;
  short* wvt = (short*)(ws + off); off += 768 * 512 * 2;
  short* wot = (short*)(ws + off); off += 512 * 512 * 2;
  short* Kb  = (short*)(ws + off); off += 1232 * 512 * 2;
  short* Vtg = (short*)(ws + off); off += (size_t)16 * 8 * 64 * 104 * 2;
  short* AOb = (short*)(ws + off); off += (size_t)65536 * 512 * 2;

  // all weight transposes + Vtg zero-fill in one dispatch
  prep_all<<<dim3(8, 12, 5), 256, 0, stream>>>(Wq, Wk, Wv, Wo,
                                               wqt, wkt, wvt, wot,
                                               (float4v*)Vtg);
  // K and V projections in one dispatch
  kvproj<<<dim3(4, 39, 2), 256, 0, stream>>>(ctx, wkt, wvt, Kb, Vtg);

  // fused Q-proj + attention -> AOb bf16 (1024 half-head blocks)
  qattn<<<1024, 512, 0, stream>>>(x, wqt, Kb, Vtg, AOb);

  // output projection + bias -> f32 d_out
  gemm2<<<2048, 256, 0, stream>>>(AOb, wot, out, bo);
}

// Round 17
// 178.517 us; speedup vs baseline: 1.0627x; 1.0080x over previous
//
#include <hip/hip_runtime.h>
#include <hip/hip_bf16.h>
#include <stdint.h>

// CrossAttention: out = softmax((x@Wq)(ctx@Wk)^T * scale) @ (ctx@Wv) @ Wo + bo
// B=16, NQ=4096, NK=77, QD=512, CD=768, H=8, DH=64, INNER=512
//
// Round 17 (vs round 16, qattn only):
//  1. W staging -> global_load_lds into linear [2][256][32] (was reg-staged
//     ds_write; W is bf16 already, no cvt needed). GLDS for step t+1 issued
//     after barrier(t), drained by barrier(t+1) -> full compute overlap.
//  2. T5 s_setprio(1) around every MFMA cluster (2 blocks/CU = wave role
//     diversity, the regime where setprio pays per m191).

typedef __attribute__((ext_vector_type(8))) short bf16x8;
typedef __attribute__((ext_vector_type(4))) float f32x4;
typedef __attribute__((ext_vector_type(4))) short short4v;
typedef __attribute__((ext_vector_type(4))) float float4v;
typedef __attribute__((ext_vector_type(2))) unsigned uint2v;
typedef __attribute__((ext_vector_type(4))) unsigned uint4v;

#define DEVINL __device__ __forceinline__

DEVINL short f2bf(float f) {
  unsigned u = __builtin_bit_cast(unsigned, f);
  unsigned r = (u + 0x7FFFu + ((u >> 16) & 1u)) >> 16;  // RNE
  return (short)(unsigned short)r;
}

// packed f32x2 -> bf16x2 (RTNE), single VALU op
DEVINL unsigned pkbf(float lo, float hi) {
  unsigned r;
  asm("v_cvt_pk_bf16_f32 %0, %1, %2" : "=v"(r) : "v"(lo), "v"(hi));
  return r;
}

#define GLDS16(gp, sp)                                                \
  __builtin_amdgcn_global_load_lds(                                   \
      (const __attribute__((address_space(1))) void*)(gp),            \
      (__attribute__((address_space(3))) void*)(sp), 16, 0, 0)

// ---------------- batched prep: 4x weight transpose + Vtg zero-fill --------
__global__ __launch_bounds__(256) void prep_all(
    const float* __restrict__ Wq, const float* __restrict__ Wk,
    const float* __restrict__ Wv, const float* __restrict__ Wo,
    short* __restrict__ wqt, short* __restrict__ wkt,
    short* __restrict__ wvt, short* __restrict__ wot,
    float4v* __restrict__ vfill) {
  const int z = blockIdx.z;
  if (z == 4) {
    for (int i = (blockIdx.y * 8 + blockIdx.x) * 256 + threadIdx.x;
         i < 106496; i += 24576)
      vfill[i] = float4v{0.f, 0.f, 0.f, 0.f};
    return;
  }
  const float* W;
  short* Wt;
  int K;
  switch (z) {
    case 0: W = Wq; Wt = wqt; K = 512; break;
    case 1: W = Wk; Wt = wkt; K = 768; break;
    case 2: W = Wv; Wt = wvt; K = 768; break;
    default: W = Wo; Wt = wot; K = 512; break;
  }
  const int kt = blockIdx.y * 64;
  if (kt >= K) return;
  const int nt = blockIdx.x * 64;

  __shared__ short Tl[64][65];
#pragma unroll
  for (int i = 0; i < 16; ++i) {
    int idx = threadIdx.x + i * 256;
    int r = idx >> 6, c = idx & 63;
    Tl[c][r] = f2bf(W[(size_t)(kt + r) * 512 + nt + c]);
  }
  __syncthreads();
#pragma unroll
  for (int i = 0; i < 16; ++i) {
    int idx = threadIdx.x + i * 256;
    int r = idx >> 6, c = idx & 63;
    Wt[(size_t)(nt + r) * K + kt + c] = Tl[r][c];
  }
}

// ---------------- K+V projections in one dispatch ---------------------------
__global__ __launch_bounds__(256) void kvproj(const float* __restrict__ A,
                                              const short* __restrict__ wkt,
                                              const short* __restrict__ wvt,
                                              short* __restrict__ Kb,
                                              short* __restrict__ Vtg) {
  __shared__ short Al[32][40];
  __shared__ short Bl[128][40];

  const int TRANS = blockIdx.z;
  const short* Bt = TRANS ? wvt : wkt;

  const int tid = threadIdx.x;
  const int lane = tid & 63, wid = tid >> 6;
  const int wm = wid >> 1, wn = wid & 1;
  const int quad = lane >> 4, l16 = lane & 15;
  const int m0 = blockIdx.y * 32, n0 = blockIdx.x * 128;
  const int M = 1232, K = 768;

  f32x4 acc[4] = {};

  for (int k0 = 0; k0 < K; k0 += 32) {
    for (int idx = tid; idx < 32 * 8; idx += 256) {
      int row = idx >> 3, kq = idx & 7;
      float4v v = {};
      if (m0 + row < M)
        v = *(const float4v*)(A + (size_t)(m0 + row) * K + k0 + kq * 4);
      short4v s = {f2bf(v[0]), f2bf(v[1]), f2bf(v[2]), f2bf(v[3])};
      *(short4v*)&Al[row][kq * 4] = s;
    }
    for (int idx = tid; idx < 512; idx += 256) {
      int row = idx >> 2, kq = idx & 3;
      *(bf16x8*)&Bl[row][kq * 8] =
          *(const bf16x8*)(Bt + (size_t)(n0 + row) * K + k0 + kq * 8);
    }
    __syncthreads();

    bf16x8 a = *(bf16x8*)&Al[wm * 16 + l16][quad * 8];
#pragma unroll
    for (int n = 0; n < 4; ++n) {
      bf16x8 b = *(bf16x8*)&Bl[wn * 64 + n * 16 + l16][quad * 8];
      acc[n] = __builtin_amdgcn_mfma_f32_16x16x32_bf16(a, b, acc[n], 0, 0, 0);
    }
    __syncthreads();
  }

#pragma unroll
  for (int n = 0; n < 4; ++n) {
    const int col = n0 + wn * 64 + n * 16 + l16;
    const int rowb = m0 + wm * 16 + quad * 4;
#pragma unroll
    for (int r = 0; r < 4; ++r) {
      const int rr = rowb + r;
      if (rr < M) {
        if (!TRANS) {
          Kb[(size_t)rr * 512 + col] = f2bf(acc[n][r]);
        } else {
          const int bb = rr / 77, key = rr - bb * 77;
          Vtg[(size_t)((bb * 8 + (col >> 6)) * 64 + (col & 63)) * 104 + key] =
              f2bf(acc[n][r]);
        }
      }
    }
  }
}

// ---------------- fused Q-proj + attention, 8-wave half-head blocks --------
// 512 thr (8 waves), grid 1024: qt = bx & 511 (128 q-rows), ch = bx >> 9
// (heads 4ch..4ch+3). Phase 1: BK=32 x16 steps; x reg-staged (cvt), W via
// GLDS linear [2][256][32]; 1 barrier/step. Phase 2: 4 iters x 1 head.
__global__ __launch_bounds__(512, 4) void qattn(const float* __restrict__ x,
                                                const short* __restrict__ wqt,
                                                const short* __restrict__ Kb,
                                                const short* __restrict__ Vtg,
                                                short* __restrict__ AOb) {
  __shared__ __align__(16) char smem[63744];
  short* xb  = (short*)smem;               // ph1: [2][128][40] bf16, 20480 B
  short* wsW = (short*)(smem + 20480);     // ph1: [2][256][32] bf16, 32768 B
  short* Qh  = (short*)smem;               // ph2: [128][72], 18432 B
  short* Kl  = (short*)(smem + 18432);     // ph2: [80][72], 11520 B
  short* Vt  = (short*)(smem + 29952);     // ph2: [64][104], 13312 B
  short* Pw  = (short*)(smem + 43264);     // ph2: [8][16][80], 20480 B

  const int tid = threadIdx.x;
  const int lane = tid & 63, w = tid >> 6;
  const int wm = w >> 2, wn = w & 3;       // phase-1 wave grid 2x4
  const int quad = lane >> 4, l16 = lane & 15;
  const int qt = blockIdx.x & 511, ch = blockIdx.x >> 9;
  const int m0 = qt * 128;
  const int b = qt >> 5;
  const int n0 = ch * 256;                 // wqt row base (heads 4ch..4ch+3)

  f32x4 acc[4][4] = {};

  // ============ phase 1: Q-proj (128 x 256), BK=32 pipelined ==========
  // x staging (reg+cvt): row = tid>>2, 8 f32 at col (tid&3)*8
  const int xrow = tid >> 2, xcol = (tid & 3) * 8;
  // W staging (GLDS): chunk cid = w*2+p; 16 rows x 32 bf16 per 1 KB chunk
  const int wlr = lane >> 2, wlc = (lane & 3) * 8;

  const float* xg = x + (size_t)(m0 + xrow) * 512 + xcol;

  float4v pxa, pxb;
  pxa = *(const float4v*)(xg);
  pxb = *(const float4v*)(xg + 4);
  // prologue: GLDS-stage W for t=0 into wsW[0]
#pragma unroll
  for (int p = 0; p < 2; ++p) {
    const int rowb = (w * 2 + p) * 16;
    GLDS16(wqt + (size_t)(n0 + rowb + wlr) * 512 + wlc, wsW + rowb * 32);
  }

  for (int t = 0; t < 16; ++t) {
    short* xbuf = xb + (t & 1) * 5120;     // 128*40
    short* wbuf = wsW + (t & 1) * 8192;    // 256*32

    uint4v u = {pkbf(pxa[0], pxa[1]), pkbf(pxa[2], pxa[3]),
                pkbf(pxb[0], pxb[1]), pkbf(pxb[2], pxb[3])};
    *(bf16x8*)&xbuf[xrow * 40 + xcol] = __builtin_bit_cast(bf16x8, u);

    __syncthreads();  // drains x ds_writes + this step's W GLDS

    if (t < 15) {
      const int k1 = (t + 1) * 32;
      // issue W GLDS for t+1 (lands by next barrier; overlaps compute)
#pragma unroll
      for (int p = 0; p < 2; ++p) {
        const int rowb = (w * 2 + p) * 16;
        GLDS16(wqt + (size_t)(n0 + rowb + wlr) * 512 + k1 + wlc,
               wsW + ((t + 1) & 1) * 8192 + rowb * 32);
      }
      pxa = *(const float4v*)(xg + k1);
      pxb = *(const float4v*)(xg + k1 + 4);
    }

    bf16x8 af[4], bfr[4];
#pragma unroll
    for (int m = 0; m < 4; ++m)
      af[m] = *(bf16x8*)&xbuf[(wm * 64 + m * 16 + l16) * 40 + quad * 8];
#pragma unroll
    for (int n = 0; n < 4; ++n)
      bfr[n] = *(bf16x8*)&wbuf[(wn * 64 + n * 16 + l16) * 32 + quad * 8];
    __builtin_amdgcn_s_setprio(1);
#pragma unroll
    for (int m = 0; m < 4; ++m)
#pragma unroll
      for (int n = 0; n < 4; ++n)
        acc[m][n] = __builtin_amdgcn_mfma_f32_16x16x32_bf16(af[m], bfr[n],
                                                            acc[m][n], 0, 0, 0);
    __builtin_amdgcn_s_setprio(0);
  }
  __syncthreads();  // phase-1 reads done before phase-2 overlay writes

  // ================= phase 2: 4 iters x 1 head =================
#pragma unroll
  for (int it = 0; it < 4; ++it) {
    if (it) __syncthreads();
    const int h = ch * 4 + it;

    // (a) Q dump: the 2 waves with wn == it own head it's columns
    if (wn == it) {
#pragma unroll
      for (int m = 0; m < 4; ++m)
#pragma unroll
        for (int n = 0; n < 4; ++n)
#pragma unroll
          for (int r = 0; r < 4; ++r)
            Qh[(wm * 64 + m * 16 + quad * 4 + r) * 72 + n * 16 + l16] =
                f2bf(acc[m][n][r]);
    }
    // (b) K stage (rows 0..76; 77..79 garbage -> masked)
    for (int idx = tid; idx < 616; idx += 512) {
      const int r = idx >> 3, cc = (idx & 7) * 8;
      *(bf16x8*)&Kl[r * 72 + cc] =
          *(const bf16x8*)(Kb + ((size_t)b * 77 + r) * 512 + h * 64 + cc);
    }
    // (c) V^T stage, linear GLDS: 13 chunks of 1 KB
    for (int cid = w; cid < 13; cid += 8)
      GLDS16(Vtg + (size_t)(b * 8 + h) * 6656 + cid * 512 + lane * 8,
             Vt + cid * 512);
    __syncthreads();

    // (d) attention: q rows w*16..+15
    bf16x8 qfr[2];
#pragma unroll
    for (int ks = 0; ks < 2; ++ks)
      qfr[ks] = *(bf16x8*)&Qh[(w * 16 + l16) * 72 + ks * 32 + quad * 8];

    f32x4 c[5] = {};
    __builtin_amdgcn_s_setprio(1);
#pragma unroll
    for (int f = 0; f < 5; ++f)
#pragma unroll
      for (int ks = 0; ks < 2; ++ks) {
        bf16x8 a = *(bf16x8*)&Kl[(f * 16 + l16) * 72 + ks * 32 + quad * 8];
        c[f] = __builtin_amdgcn_mfma_f32_16x16x32_bf16(a, qfr[ks], c[f], 0, 0, 0);
      }
    __builtin_amdgcn_s_setprio(0);

    float mx = -1e30f;
#pragma unroll
    for (int f = 0; f < 5; ++f)
#pragma unroll
      for (int r = 0; r < 4; ++r) {
        const int key = f * 16 + quad * 4 + r;
        float v = c[f][r] * 0.125f;
        v = (key < 77) ? v : -1e30f;
        c[f][r] = v;
        mx = fmaxf(mx, v);
      }
    mx = fmaxf(mx, __shfl_xor(mx, 16));
    mx = fmaxf(mx, __shfl_xor(mx, 32));

    short* pbase = Pw + (w * 16 + l16) * 80;
    float sum = 0.f;
#pragma unroll
    for (int f = 0; f < 5; ++f) {
      float e0 = __expf(c[f][0] - mx), e1 = __expf(c[f][1] - mx);
      float e2 = __expf(c[f][2] - mx), e3 = __expf(c[f][3] - mx);
      sum += (e0 + e1) + (e2 + e3);
      uint2v sv2 = {pkbf(e0, e1), pkbf(e2, e3)};
      *(uint2v*)(pbase + f * 16 + quad * 4) = sv2;
    }
    sum += __shfl_xor(sum, 16);
    sum += __shfl_xor(sum, 32);
    const float inv = 1.0f / sum;

    bf16x8 pb0 = *(bf16x8*)(pbase + quad * 8);
    bf16x8 pb1 = *(bf16x8*)(pbase + 32 + quad * 8);
    bf16x8 pb2 = bf16x8{0, 0, 0, 0, 0, 0, 0, 0};
    if (quad < 2) pb2 = *(bf16x8*)(pbase + 64 + quad * 8);

    f32x4 o[4] = {};
    __builtin_amdgcn_s_setprio(1);
#pragma unroll
    for (int mt = 0; mt < 4; ++mt) {
      const short* vrow = &Vt[(mt * 16 + l16) * 104];
      o[mt] = __builtin_amdgcn_mfma_f32_16x16x32_bf16(
          *(bf16x8*)(vrow + quad * 8), pb0, o[mt], 0, 0, 0);
      o[mt] = __builtin_amdgcn_mfma_f32_16x16x32_bf16(
          *(bf16x8*)(vrow + 32 + quad * 8), pb1, o[mt], 0, 0, 0);
      o[mt] = __builtin_amdgcn_mfma_f32_16x16x32_bf16(
          *(bf16x8*)(vrow + 64 + quad * 8), pb2, o[mt], 0, 0, 0);
    }
    __builtin_amdgcn_s_setprio(0);

    short* op = AOb + ((size_t)m0 + w * 16 + l16) * 512 + h * 64;
#pragma unroll
    for (int mt = 0; mt < 4; ++mt) {
      uint2v sv2 = {pkbf(o[mt][0] * inv, o[mt][1] * inv),
                    pkbf(o[mt][2] * inv, o[mt][3] * inv)};
      *(uint2v*)(op + mt * 16 + quad * 4) = sv2;
    }
  }
}

// ---------------- O-proj: 2-phase dbuf GEMM, bf16 A/B, BK=32 ---------------
__global__ __launch_bounds__(256) void gemm2(const short* __restrict__ A,
                                             const short* __restrict__ Bt,
                                             float* __restrict__ C,
                                             const float* __restrict__ bias) {
  __shared__ short As[2][128 * 32];
  __shared__ short Bs[2][128 * 32];

  const int tid = threadIdx.x;
  const int lane = tid & 63, w = tid >> 6;
  const int wm = w >> 1, wn = w & 1;
  const int quad = lane >> 4, l16 = lane & 15;

  const int cpx = gridDim.x >> 3;
  const int swz = (blockIdx.x & 7) * cpx + (blockIdx.x >> 3);
  const int m0 = (swz >> 2) * 128, n0 = (swz & 3) * 128;

  const int lr = lane >> 2, lc = (lane & 3) * 8;

  f32x4 acc[4][4] = {};

#pragma unroll
  for (int p = 0; p < 2; ++p) {
    const int rowb = (w * 2 + p) * 16;
    GLDS16(A + (size_t)(m0 + rowb + lr) * 512 + lc, &As[0][rowb * 32]);
    GLDS16(Bt + (size_t)(n0 + rowb + lr) * 512 + lc, &Bs[0][rowb * 32]);
  }
  __syncthreads();

  for (int t = 0; t < 16; ++t) {
    const int cur = t & 1;
    if (t < 15) {
      const int k1 = (t + 1) * 32;
#pragma unroll
      for (int p = 0; p < 2; ++p) {
        const int rowb = (w * 2 + p) * 16;
        GLDS16(A + (size_t)(m0 + rowb + lr) * 512 + k1 + lc,
               &As[cur ^ 1][rowb * 32]);
        GLDS16(Bt + (size_t)(n0 + rowb + lr) * 512 + k1 + lc,
               &Bs[cur ^ 1][rowb * 32]);
      }
    }
    bf16x8 af[4], bfr[4];
#pragma unroll
    for (int m = 0; m < 4; ++m)
      af[m] = *(bf16x8*)&As[cur][(wm * 64 + m * 16 + l16) * 32 + quad * 8];
#pragma unroll
    for (int n = 0; n < 4; ++n)
      bfr[n] = *(bf16x8*)&Bs[cur][(wn * 64 + n * 16 + l16) * 32 + quad * 8];
#pragma unroll
    for (int m = 0; m < 4; ++m)
#pragma unroll
      for (int n = 0; n < 4; ++n)
        acc[m][n] = __builtin_amdgcn_mfma_f32_16x16x32_bf16(af[m], bfr[n],
                                                            acc[m][n], 0, 0, 0);
    if (t < 15) __syncthreads();
  }

#pragma unroll
  for (int m = 0; m < 4; ++m)
#pragma unroll
    for (int n = 0; n < 4; ++n) {
      const int col = n0 + wn * 64 + n * 16 + l16;
      const int rowb = m0 + wm * 64 + m * 16 + quad * 4;
      const float badd = bias[col];
#pragma unroll
      for (int r = 0; r < 4; ++r)
        C[(size_t)(rowb + r) * 512 + col] = acc[m][n][r] + badd;
    }
}

extern "C" void kernel_launch(void* const* d_in, const int* in_sizes, int n_in,
                              void* d_out, int out_size, void* d_ws, size_t ws_size,
                              hipStream_t stream) {
  const float* x   = (const float*)d_in[0];
  const float* ctx = (const float*)d_in[1];
  const float* Wq  = (const float*)d_in[2];
  const float* Wk  = (const float*)d_in[3];
  const float* Wv  = (const float*)d_in[4];
  const float* Wo  = (const float*)d_in[5];
  const float* bo  = (const float*)d_in[6];
  float* out = (float*)d_out;

  char* ws = (char*)d_ws;
  size_t off = 0;
  short* wqt = (short*)(ws + off); off += 512 * 512 * 2;
  short* wkt = (short*)(ws + off); off += 768 * 512 * 2;
  short* wvt = (short*)(ws + off); off += 768 * 512 * 2;
  short* wot = (short*)(ws + off); off += 512 * 512 * 2;
  short* Kb  = (short*)(ws + off); off += 1232 * 512 * 2;
  short* Vtg = (short*)(ws + off); off += (size_t)16 * 8 * 64 * 104 * 2;
  short* AOb = (short*)(ws + off); off += (size_t)65536 * 512 * 2;

  // all weight transposes + Vtg zero-fill in one dispatch
  prep_all<<<dim3(8, 12, 5), 256, 0, stream>>>(Wq, Wk, Wv, Wo,
                                               wqt, wkt, wvt, wot,
                                               (float4v*)Vtg);
  // K and V projections in one dispatch
  kvproj<<<dim3(4, 39, 2), 256, 0, stream>>>(ctx, wkt, wvt, Kb, Vtg);

  // fused Q-proj + attention -> AOb bf16 (1024 half-head blocks)
  qattn<<<1024, 512, 0, stream>>>(x, wqt, Kb, Vtg, AOb);

  // output projection + bias -> f32 d_out
  gemm2<<<2048, 256, 0, stream>>>(AOb, wot, out, bo);
}